// Round 2
// baseline (411.334 us; speedup 1.0000x reference)
//
#include <hip/hip_runtime.h>
#include <hip/hip_bf16.h>
#include <math.h>

#define K 4
#define F 513
#define B 4000
#define NIT 5
#define FB (F*B)
#define KB (K*B)
#define DFC 4         // f-chunk for demix/final (4 f per thread, grid y=129)
#define NDF 129       // ceil(513/4)
#define NBC 8         // b-chunks for v_kernel (B divisible: 4000/8=500)
#define BCH (B/NBC)   // 500 -> 250 two-b slots, single iteration per thread

// ---------------- persistent scratch: static device globals ------------------
__device__ float2 g_Wh[F*16];        // (F,4,4) complex fp32
__device__ float2 g_Vp[NBC*64*F];    // per-b-chunk partial V: (y, k*16+q, f)
__device__ float2 g_scale[F*4];      // (F,4) complex fp32
__device__ float  g_r2p[NDF*KB];     // per-f-chunk partials (plain stores, no init needed)
__device__ float4 g_phiT[B];         // phi[b] = (phi_k0..phi_k3), one 16B load in v_kernel

// ---------------- complex double helpers (tiny per-f solves only) -----------
struct cd { double re, im; };
__device__ inline cd mkcd(double r, double i){ cd z; z.re=r; z.im=i; return z; }
__device__ inline cd cmul(cd a, cd b){ return mkcd(a.re*b.re - a.im*b.im, a.re*b.im + a.im*b.re); }
__device__ inline cd cadd(cd a, cd b){ return mkcd(a.re+b.re, a.im+b.im); }
__device__ inline cd csub(cd a, cd b){ return mkcd(a.re-b.re, a.im-b.im); }
__device__ inline cd conj_(cd a){ return mkcd(a.re, -a.im); }
__device__ inline cd cdiv(cd a, cd b){
  double d = b.re*b.re + b.im*b.im;
  return mkcd((a.re*b.re + a.im*b.im)/d, (a.im*b.re - a.re*b.im)/d);
}

// x = inv(M)[:,kk] via cofactors (branch-free, no pivoting).
__device__ inline void invcol4(const cd M[4][4], int kk, cd x[4]){
  int r0 = (kk==0)?1:0;
  int r1 = (kk<=1)?2:1;
  int r2 = (kk<=2)?3:2;
  cd cof[4];
  #pragma unroll
  for (int i=0;i<4;++i){
    int c0 = (i==0)?1:0;
    int c1 = (i<=1)?2:1;
    int c2 = (i<=2)?3:2;
    cd m = cadd(csub(cmul(M[r0][c0], csub(cmul(M[r1][c1],M[r2][c2]), cmul(M[r1][c2],M[r2][c1]))),
                     cmul(M[r0][c1], csub(cmul(M[r1][c0],M[r2][c2]), cmul(M[r1][c2],M[r2][c0])))),
                cmul(M[r0][c2], csub(cmul(M[r1][c0],M[r2][c1]), cmul(M[r1][c1],M[r2][c0]))));
    if ((kk+i)&1) m = mkcd(-m.re,-m.im);
    cof[i] = m;
  }
  cd det = mkcd(0.0,0.0);
  #pragma unroll
  for (int i=0;i<4;++i) det = cadd(det, cmul(M[kk][i], cof[i]));
  cd idet = cdiv(mkcd(1.0,0.0), det);
  #pragma unroll
  for (int i=0;i<4;++i) x[i] = cmul(cof[i], idet);
}

// ---------------- kernels ---------------------------------------------------

__global__ void init_kernel(){
  int t = blockIdx.x*blockDim.x + threadIdx.x;
  if (t < F*16){
    int sc = t & 15; int s = sc >> 2, c = sc & 3;
    g_Wh[t] = make_float2(s==c ? 1.0f : 0.0f, 0.0f);
  }
}

// partial r2: r2p[y,k,b] = sum over f-chunk y of |(Wh[f] X[:,f,b])[k]|^2
// 2 consecutive b per thread via float2 loads (8B/lane).
__global__ __launch_bounds__(256) void demix_part_kernel(
    const float* __restrict__ Xr, const float* __restrict__ Xi){
  int t = blockIdx.x*blockDim.x + threadIdx.x;
  if (t >= B/2) return;
  int b = 2*t;
  int y = blockIdx.y;
  int f0 = y*DFC, f1 = min(f0+DFC, F);
  float acc0[K], acc1[K];
  #pragma unroll
  for (int s=0;s<K;++s){ acc0[s]=0.0f; acc1[s]=0.0f; }
  for (int f=f0; f<f1; ++f){
    float2 xr[K], xi[K];
    #pragma unroll
    for (int c=0;c<K;++c){
      int idx = c*FB + f*B + b;
      xr[c] = *reinterpret_cast<const float2*>(Xr + idx);
      xi[c] = *reinterpret_cast<const float2*>(Xi + idx);
    }
    const float2* w = g_Wh + f*16;   // f uniform per block -> scalar loads
    #pragma unroll
    for (int s=0;s<K;++s){
      float yr0=0.0f, yi0=0.0f, yr1=0.0f, yi1=0.0f;
      #pragma unroll
      for (int c=0;c<K;++c){
        float2 ww = w[s*4+c];
        yr0 += ww.x*xr[c].x - ww.y*xi[c].x;
        yi0 += ww.x*xi[c].x + ww.y*xr[c].x;
        yr1 += ww.x*xr[c].y - ww.y*xi[c].y;
        yi1 += ww.x*xi[c].y + ww.y*xr[c].y;
      }
      acc0[s] += yr0*yr0 + yi0*yi0;
      acc1[s] += yr1*yr1 + yi1*yi1;
    }
  }
  #pragma unroll
  for (int s=0;s<K;++s)
    *reinterpret_cast<float2*>(g_r2p + y*KB + s*B + b) = make_float2(acc0[s], acc1[s]);
}

// phiT[b][k] = 0.5 / sqrt( sum_y r2p[y,k,b] ) — transposed so v_kernel does
// one float4 load per b. Numerics: same 0.5f/sqrtf on the same (reordered) sum.
__global__ __launch_bounds__(256) void phi_kernel(){
  int b = blockIdx.x*blockDim.x + threadIdx.x;
  if (b >= B) return;
  int k = blockIdx.y;
  float s = 0.0f;
  #pragma unroll 8
  for (int y=0; y<NDF; ++y) s += g_r2p[y*KB + k*B + b];
  reinterpret_cast<float*>(g_phiT)[b*4 + k] = 0.5f / sqrtf(s);
}

// Partial V over a b-chunk: Vp[y,k,ij,f] = (1/B) sum_{b in chunk y} phi[k,b] p[ij](f,b)
// Grid (F, NBC=8) -> 4104 blocks; each thread: exactly one 2-b iteration (float2 loads).
__global__ __launch_bounds__(256, 4) void v_kernel(
    const float* __restrict__ Xr, const float* __restrict__ Xi){
  int f = blockIdx.x;
  int y = blockIdx.y;
  int tid = threadIdx.x;
  float acc[64];
  #pragma unroll
  for (int q=0;q<64;++q) acc[q]=0.0f;

  if (tid < BCH/2){
    int b = y*BCH + 2*tid;
    float4 ph0 = g_phiT[b];
    float4 ph1 = g_phiT[b+1];
    float pk0[K] = {ph0.x, ph0.y, ph0.z, ph0.w};
    float pk1[K] = {ph1.x, ph1.y, ph1.z, ph1.w};
    float2 xr[K], xi[K];
    #pragma unroll
    for (int c=0;c<K;++c){
      int idx = c*FB + f*B + b;
      xr[c] = *reinterpret_cast<const float2*>(Xr + idx);
      xi[c] = *reinterpret_cast<const float2*>(Xi + idx);
    }
    // b even (.x components)
    {
      float p[16];
      #pragma unroll
      for (int i=0;i<4;++i) p[i] = xr[i].x*xr[i].x + xi[i].x*xi[i].x;
      int s = 4;
      #pragma unroll
      for (int i=0;i<4;++i){
        #pragma unroll
        for (int j=i+1;j<4;++j){
          p[s++] = xr[i].x*xr[j].x + xi[i].x*xi[j].x;
          p[s++] = xi[i].x*xr[j].x - xr[i].x*xi[j].x;
        }
      }
      #pragma unroll
      for (int k=0;k<K;++k){
        #pragma unroll
        for (int q=0;q<16;++q) acc[k*16+q] += pk0[k]*p[q];
      }
    }
    // b odd (.y components)
    {
      float p[16];
      #pragma unroll
      for (int i=0;i<4;++i) p[i] = xr[i].y*xr[i].y + xi[i].y*xi[i].y;
      int s = 4;
      #pragma unroll
      for (int i=0;i<4;++i){
        #pragma unroll
        for (int j=i+1;j<4;++j){
          p[s++] = xr[i].y*xr[j].y + xi[i].y*xi[j].y;
          p[s++] = xi[i].y*xr[j].y - xr[i].y*xi[j].y;
        }
      }
      #pragma unroll
      for (int k=0;k<K;++k){
        #pragma unroll
        for (int q=0;q<16;++q) acc[k*16+q] += pk1[k]*p[q];
      }
    }
  }

  int lane = tid & 63, wave = tid >> 6;
  // Multi-value butterfly: 63 shfl_xor; after 6 steps lane l holds (in acc[0])
  // the wave-wide sum of original acc[l]. All lanes participate (idle lanes = 0).
  #pragma unroll
  for (int d=0; d<6; ++d){
    const int sh = 1<<d;
    const bool hi = (lane & sh) != 0;
    #pragma unroll
    for (int m=0; m<(32>>d); ++m){
      float keep = hi ? acc[2*m+1] : acc[2*m];   // static indices: no scratch
      float send = hi ? acc[2*m]   : acc[2*m+1];
      acc[m] = keep + __shfl_xor(send, sh);
    }
  }

  __shared__ float part[4*64];
  __shared__ float red[64];
  part[wave*64 + lane] = acc[0];
  __syncthreads();
  if (tid < 64){
    red[tid] = (part[tid] + part[64+tid] + part[128+tid] + part[192+tid]) * (1.0f/B);
  }
  __syncthreads();
  if (tid < 64){
    int k = tid >> 4, ij = tid & 15, i = ij >> 2, j = ij & 3;
    float re, im;
    if (i == j){ re = red[k*16 + i]; im = 0.0f; }
    else {
      int a = min(i,j), c2 = max(i,j);
      int pidx = (a==0) ? (c2-1) : ((a==1) ? (c2+1) : 5);
      re = red[k*16 + 4 + 2*pidx];
      im = red[k*16 + 5 + 2*pidx];
      if (i > j) im = -im;
    }
    g_Vp[(y*64 + (unsigned)tid)*F + f] = make_float2(re, im);
  }
}

// Per-f IP updates k=0..3 (sequential), fp64 cofactor solves, branch-free.
// Absorbs the NBC-way V-partial reduction (coalesced L2-cached loads).
__global__ __launch_bounds__(64) void update_kernel(int do_scale){
  int f = blockIdx.x*blockDim.x + threadIdx.x;
  if (f >= F) return;
  cd W[4][4];
  #pragma unroll
  for (int s=0;s<4;++s)
    #pragma unroll
    for (int c=0;c<4;++c){ float2 w = g_Wh[f*16+s*4+c]; W[s][c] = mkcd((double)w.x,(double)w.y); }

  #pragma unroll
  for (int k=0;k<4;++k){
    cd Vk[4][4];
    #pragma unroll
    for (int i=0;i<4;++i)
      #pragma unroll
      for (int j=0;j<4;++j){
        float2 vv = make_float2(0.0f, 0.0f);
        #pragma unroll
        for (int y=0;y<NBC;++y){
          float2 t2 = g_Vp[(y*64 + (k*4+i)*4 + j)*F + f];
          vv.x += t2.x; vv.y += t2.y;
        }
        Vk[i][j] = mkcd((double)vv.x,(double)vv.y);
      }
    cd M[4][4];
    #pragma unroll
    for (int i=0;i<4;++i)
      #pragma unroll
      for (int j=0;j<4;++j){
        cd s = mkcd(0.0,0.0);
        #pragma unroll
        for (int c=0;c<4;++c) s = cadd(s, cmul(W[i][c], Vk[c][j]));
        M[i][j] = s;
      }
    cd x[4];
    invcol4(M, k, x);                  // x = inv(M)[:,k]
    cd w[4];
    #pragma unroll
    for (int c=0;c<4;++c) w[c] = conj_(x[c]);
    double dre = 0.0;
    #pragma unroll
    for (int j=0;j<4;++j){
      cd tj = mkcd(0.0,0.0);
      #pragma unroll
      for (int c=0;c<4;++c) tj = cadd(tj, cmul(w[c], Vk[c][j]));
      dre += tj.re*w[j].re + tj.im*w[j].im;   // Re(tj * conj(w_j))
    }
    double inv_denom = rsqrt(dre > 0.0 ? dre : 1e-300);
    #pragma unroll
    for (int c=0;c<4;++c) W[k][c] = mkcd(w[c].re*inv_denom, w[c].im*inv_denom);
  }
  #pragma unroll
  for (int s=0;s<4;++s)
    #pragma unroll
    for (int c=0;c<4;++c) g_Wh[f*16+s*4+c] = make_float2((float)W[s][c].re, (float)W[s][c].im);

  if (do_scale){
    cd x[4];
    invcol4(W, 0, x);   // x = inv(Wh)[:,0]
    #pragma unroll
    for (int s=0;s<4;++s) g_scale[f*4+s] = make_float2((float)x[s].re, (float)x[s].im);
  }
}

// out[s,f,b] = (Wh[f] X[:,f,b])[s] * scale[f,s]; 2 b per thread, 8B packed stores
__global__ __launch_bounds__(256) void final_kernel(
    const float* __restrict__ Xr, const float* __restrict__ Xi,
    __hip_bfloat162* __restrict__ out){
  int t = blockIdx.x*blockDim.x + threadIdx.x;
  if (t >= B/2) return;
  int b = 2*t;
  int f0 = blockIdx.y*DFC, f1 = min(f0+DFC, F);
  for (int f=f0; f<f1; ++f){
    float2 xr[K], xi[K];
    #pragma unroll
    for (int c=0;c<K;++c){
      int idx = c*FB + f*B + b;
      xr[c] = *reinterpret_cast<const float2*>(Xr + idx);
      xi[c] = *reinterpret_cast<const float2*>(Xi + idx);
    }
    const float2* w = g_Wh + f*16;
    #pragma unroll
    for (int s=0;s<K;++s){
      float yr0=0.0f, yi0=0.0f, yr1=0.0f, yi1=0.0f;
      #pragma unroll
      for (int c=0;c<K;++c){
        float2 ww = w[s*4+c];
        yr0 += ww.x*xr[c].x - ww.y*xi[c].x;
        yi0 += ww.x*xi[c].x + ww.y*xr[c].x;
        yr1 += ww.x*xr[c].y - ww.y*xi[c].y;
        yi1 += ww.x*xi[c].y + ww.y*xr[c].y;
      }
      float2 sc = g_scale[f*4+s];
      union { __hip_bfloat162 h2[2]; uint2 u; } uu;
      uu.h2[0].x = __float2bfloat16(yr0*sc.x - yi0*sc.y);
      uu.h2[0].y = __float2bfloat16(yr0*sc.y + yi0*sc.x);
      uu.h2[1].x = __float2bfloat16(yr1*sc.x - yi1*sc.y);
      uu.h2[1].y = __float2bfloat16(yr1*sc.y + yi1*sc.x);
      *reinterpret_cast<uint2*>(out + s*FB + f*B + b) = uu.u;
    }
  }
}

// ---------------- launch ----------------------------------------------------
extern "C" void kernel_launch(void* const* d_in, const int* in_sizes, int n_in,
                              void* d_out, int out_size, void* d_ws, size_t ws_size,
                              hipStream_t stream){
  // Inputs arrive alphabetized: d_in[0]="Xi", d_in[1]="Xr".
  const float* Xr = (const float*)d_in[1];
  const float* Xi = (const float*)d_in[0];
  __hip_bfloat162* out = (__hip_bfloat162*)d_out;

  init_kernel<<<33, 256, 0, stream>>>();
  dim3 gD((B/2 + 255)/256, NDF);        // (8, 129)
  dim3 gP((B + 255)/256, K);            // (16, 4)
  dim3 gV(F, NBC);                      // (513, 8)
  for (int it=0; it<NIT; ++it){
    demix_part_kernel<<<gD, 256, 0, stream>>>(Xr, Xi);
    phi_kernel<<<gP, 256, 0, stream>>>();
    v_kernel<<<gV, 256, 0, stream>>>(Xr, Xi);
    update_kernel<<<(F + 63)/64, 64, 0, stream>>>(it == NIT-1 ? 1 : 0);
  }
  final_kernel<<<gD, 256, 0, stream>>>(Xr, Xi, out);
}

// Round 3
// 373.730 us; speedup vs baseline: 1.1006x; 1.1006x over previous
//
#include <hip/hip_runtime.h>
#include <hip/hip_bf16.h>
#include <math.h>

#define K 4
#define F 513
#define B 4000
#define NIT 5
#define FB (F*B)
#define KB (K*B)
#define DFC 4         // f-chunk for demix/final (4 f per thread, grid y=129)
#define NDF 129       // ceil(513/4)
#define NBC 8         // b-chunks for v_kernel (B divisible: 4000/8=500)
#define BCH (B/NBC)   // 500 -> 250 two-b slots, single iteration per thread

// ---------------- persistent scratch: static device globals ------------------
__device__ float2 g_Wh[F*16];        // (F,4,4) complex fp32
__device__ float2 g_Vp[NBC*64*F];    // per-b-chunk partial V: (y, k*16+q, f)
__device__ float2 g_V[64*F];         // reduced V: (k*16+q, f)
__device__ float2 g_scale[F*4];      // (F,4) complex fp32
__device__ float  g_r2p[NDF*KB];     // per-f-chunk partials (plain stores, no init needed)
__device__ float4 g_phiT[B];         // phi[b] = (phi_k0..phi_k3), one 16B load in v_kernel

// ---------------- complex double helpers (tiny per-f solves only) -----------
struct cd { double re, im; };
__device__ inline cd mkcd(double r, double i){ cd z; z.re=r; z.im=i; return z; }
__device__ inline cd cmul(cd a, cd b){ return mkcd(a.re*b.re - a.im*b.im, a.re*b.im + a.im*b.re); }
__device__ inline cd cadd(cd a, cd b){ return mkcd(a.re+b.re, a.im+b.im); }
__device__ inline cd csub(cd a, cd b){ return mkcd(a.re-b.re, a.im-b.im); }
__device__ inline cd conj_(cd a){ return mkcd(a.re, -a.im); }
__device__ inline cd cdiv(cd a, cd b){
  double d = b.re*b.re + b.im*b.im;
  return mkcd((a.re*b.re + a.im*b.im)/d, (a.im*b.re - a.re*b.im)/d);
}

// x = inv(M)[:,kk] via cofactors (branch-free, no pivoting).
__device__ inline void invcol4(const cd M[4][4], int kk, cd x[4]){
  int r0 = (kk==0)?1:0;
  int r1 = (kk<=1)?2:1;
  int r2 = (kk<=2)?3:2;
  cd cof[4];
  #pragma unroll
  for (int i=0;i<4;++i){
    int c0 = (i==0)?1:0;
    int c1 = (i<=1)?2:1;
    int c2 = (i<=2)?3:2;
    cd m = cadd(csub(cmul(M[r0][c0], csub(cmul(M[r1][c1],M[r2][c2]), cmul(M[r1][c2],M[r2][c1]))),
                     cmul(M[r0][c1], csub(cmul(M[r1][c0],M[r2][c2]), cmul(M[r1][c2],M[r2][c0])))),
                cmul(M[r0][c2], csub(cmul(M[r1][c0],M[r2][c1]), cmul(M[r1][c1],M[r2][c0]))));
    if ((kk+i)&1) m = mkcd(-m.re,-m.im);
    cof[i] = m;
  }
  cd det = mkcd(0.0,0.0);
  #pragma unroll
  for (int i=0;i<4;++i) det = cadd(det, cmul(M[kk][i], cof[i]));
  cd idet = cdiv(mkcd(1.0,0.0), det);
  #pragma unroll
  for (int i=0;i<4;++i) x[i] = cmul(cof[i], idet);
}

// ---------------- kernels ---------------------------------------------------

__global__ void init_kernel(){
  int t = blockIdx.x*blockDim.x + threadIdx.x;
  if (t < F*16){
    int sc = t & 15; int s = sc >> 2, c = sc & 3;
    g_Wh[t] = make_float2(s==c ? 1.0f : 0.0f, 0.0f);
  }
}

// partial r2: r2p[y,k,b] = sum over f-chunk y of |(Wh[f] X[:,f,b])[k]|^2
// 2 consecutive b per thread via float2 loads (8B/lane).
__global__ __launch_bounds__(256) void demix_part_kernel(
    const float* __restrict__ Xr, const float* __restrict__ Xi){
  int t = blockIdx.x*blockDim.x + threadIdx.x;
  if (t >= B/2) return;
  int b = 2*t;
  int y = blockIdx.y;
  int f0 = y*DFC, f1 = min(f0+DFC, F);
  float acc0[K], acc1[K];
  #pragma unroll
  for (int s=0;s<K;++s){ acc0[s]=0.0f; acc1[s]=0.0f; }
  for (int f=f0; f<f1; ++f){
    float2 xr[K], xi[K];
    #pragma unroll
    for (int c=0;c<K;++c){
      int idx = c*FB + f*B + b;
      xr[c] = *reinterpret_cast<const float2*>(Xr + idx);
      xi[c] = *reinterpret_cast<const float2*>(Xi + idx);
    }
    const float2* w = g_Wh + f*16;   // f uniform per block -> scalar loads
    #pragma unroll
    for (int s=0;s<K;++s){
      float yr0=0.0f, yi0=0.0f, yr1=0.0f, yi1=0.0f;
      #pragma unroll
      for (int c=0;c<K;++c){
        float2 ww = w[s*4+c];
        yr0 += ww.x*xr[c].x - ww.y*xi[c].x;
        yi0 += ww.x*xi[c].x + ww.y*xr[c].x;
        yr1 += ww.x*xr[c].y - ww.y*xi[c].y;
        yi1 += ww.x*xi[c].y + ww.y*xr[c].y;
      }
      acc0[s] += yr0*yr0 + yi0*yi0;
      acc1[s] += yr1*yr1 + yi1*yi1;
    }
  }
  #pragma unroll
  for (int s=0;s<K;++s)
    *reinterpret_cast<float2*>(g_r2p + y*KB + s*B + b) = make_float2(acc0[s], acc1[s]);
}

// phiT[b][k] = 0.5 / sqrt( sum_y r2p[y,k,b] ) — transposed so v_kernel does
// one float4 load per b.
__global__ __launch_bounds__(256) void phi_kernel(){
  int b = blockIdx.x*blockDim.x + threadIdx.x;
  if (b >= B) return;
  int k = blockIdx.y;
  float s = 0.0f;
  #pragma unroll 8
  for (int y=0; y<NDF; ++y) s += g_r2p[y*KB + k*B + b];
  reinterpret_cast<float*>(g_phiT)[b*4 + k] = 0.5f / sqrtf(s);
}

// Partial V over a b-chunk: Vp[y,k,ij,f] = (1/B) sum_{b in chunk y} phi[k,b] p[ij](f,b)
// Grid (F, NBC=8) -> 4104 blocks; each thread: exactly one 2-b iteration (float2 loads).
__global__ __launch_bounds__(256, 4) void v_kernel(
    const float* __restrict__ Xr, const float* __restrict__ Xi){
  int f = blockIdx.x;
  int y = blockIdx.y;
  int tid = threadIdx.x;
  float acc[64];
  #pragma unroll
  for (int q=0;q<64;++q) acc[q]=0.0f;

  if (tid < BCH/2){
    int b = y*BCH + 2*tid;
    float4 ph0 = g_phiT[b];
    float4 ph1 = g_phiT[b+1];
    float pk0[K] = {ph0.x, ph0.y, ph0.z, ph0.w};
    float pk1[K] = {ph1.x, ph1.y, ph1.z, ph1.w};
    float2 xr[K], xi[K];
    #pragma unroll
    for (int c=0;c<K;++c){
      int idx = c*FB + f*B + b;
      xr[c] = *reinterpret_cast<const float2*>(Xr + idx);
      xi[c] = *reinterpret_cast<const float2*>(Xi + idx);
    }
    // b even (.x components)
    {
      float p[16];
      #pragma unroll
      for (int i=0;i<4;++i) p[i] = xr[i].x*xr[i].x + xi[i].x*xi[i].x;
      int s = 4;
      #pragma unroll
      for (int i=0;i<4;++i){
        #pragma unroll
        for (int j=i+1;j<4;++j){
          p[s++] = xr[i].x*xr[j].x + xi[i].x*xi[j].x;
          p[s++] = xi[i].x*xr[j].x - xr[i].x*xi[j].x;
        }
      }
      #pragma unroll
      for (int k=0;k<K;++k){
        #pragma unroll
        for (int q=0;q<16;++q) acc[k*16+q] += pk0[k]*p[q];
      }
    }
    // b odd (.y components)
    {
      float p[16];
      #pragma unroll
      for (int i=0;i<4;++i) p[i] = xr[i].y*xr[i].y + xi[i].y*xi[i].y;
      int s = 4;
      #pragma unroll
      for (int i=0;i<4;++i){
        #pragma unroll
        for (int j=i+1;j<4;++j){
          p[s++] = xr[i].y*xr[j].y + xi[i].y*xi[j].y;
          p[s++] = xi[i].y*xr[j].y - xr[i].y*xi[j].y;
        }
      }
      #pragma unroll
      for (int k=0;k<K;++k){
        #pragma unroll
        for (int q=0;q<16;++q) acc[k*16+q] += pk1[k]*p[q];
      }
    }
  }

  int lane = tid & 63, wave = tid >> 6;
  // Multi-value butterfly: 63 shfl_xor; after 6 steps lane l holds (in acc[0])
  // the wave-wide sum of original acc[l]. All lanes participate (idle lanes = 0).
  #pragma unroll
  for (int d=0; d<6; ++d){
    const int sh = 1<<d;
    const bool hi = (lane & sh) != 0;
    #pragma unroll
    for (int m=0; m<(32>>d); ++m){
      float keep = hi ? acc[2*m+1] : acc[2*m];   // static indices: no scratch
      float send = hi ? acc[2*m]   : acc[2*m+1];
      acc[m] = keep + __shfl_xor(send, sh);
    }
  }

  __shared__ float part[4*64];
  __shared__ float red[64];
  part[wave*64 + lane] = acc[0];
  __syncthreads();
  if (tid < 64){
    red[tid] = (part[tid] + part[64+tid] + part[128+tid] + part[192+tid]) * (1.0f/B);
  }
  __syncthreads();
  if (tid < 64){
    int k = tid >> 4, ij = tid & 15, i = ij >> 2, j = ij & 3;
    float re, im;
    if (i == j){ re = red[k*16 + i]; im = 0.0f; }
    else {
      int a = min(i,j), c2 = max(i,j);
      int pidx = (a==0) ? (c2-1) : ((a==1) ? (c2+1) : 5);
      re = red[k*16 + 4 + 2*pidx];
      im = red[k*16 + 5 + 2*pidx];
      if (i > j) im = -im;
    }
    g_Vp[(y*64 + (unsigned)tid)*F + f] = make_float2(re, im);
  }
}

// Reduce the NBC partial V's with full TLP + perfectly coalesced accesses.
// (Lesson from last round: folding this into the 9-block update_kernel made a
// 113 µs latency-bound serial chain; here it's 32832 threads, ~4 µs.)
__global__ __launch_bounds__(256) void reduce_v_kernel(){
  int t = blockIdx.x*blockDim.x + threadIdx.x;   // t = q*F + f
  if (t >= 64*F) return;
  float2 s = make_float2(0.0f, 0.0f);
  #pragma unroll
  for (int y=0; y<NBC; ++y){
    float2 v = g_Vp[y*64*F + t];
    s.x += v.x; s.y += v.y;
  }
  g_V[t] = s;
}

// Per-f IP updates k=0..3 (sequential), fp64 cofactor solves, branch-free.
// All 64 complex V entries prefetched in one unrolled coalesced batch so the
// ~500cy load latency is paid once, not 64 times. launch_bounds(64,1) keeps
// the ~250-VGPR prefetch from spilling (occupancy irrelevant: 9 blocks).
__global__ __launch_bounds__(64, 1) void update_kernel(int do_scale){
  int f = blockIdx.x*blockDim.x + threadIdx.x;
  if (f >= F) return;

  float2 Vf[64];
  #pragma unroll
  for (int q=0;q<64;++q) Vf[q] = g_V[q*F + f];

  cd W[4][4];
  #pragma unroll
  for (int s=0;s<4;++s)
    #pragma unroll
    for (int c=0;c<4;++c){ float2 w = g_Wh[f*16+s*4+c]; W[s][c] = mkcd((double)w.x,(double)w.y); }

  #pragma unroll
  for (int k=0;k<4;++k){
    cd Vk[4][4];
    #pragma unroll
    for (int i=0;i<4;++i)
      #pragma unroll
      for (int j=0;j<4;++j){
        float2 vv = Vf[(k*4+i)*4+j];
        Vk[i][j] = mkcd((double)vv.x,(double)vv.y);
      }
    cd M[4][4];
    #pragma unroll
    for (int i=0;i<4;++i)
      #pragma unroll
      for (int j=0;j<4;++j){
        cd s = mkcd(0.0,0.0);
        #pragma unroll
        for (int c=0;c<4;++c) s = cadd(s, cmul(W[i][c], Vk[c][j]));
        M[i][j] = s;
      }
    cd x[4];
    invcol4(M, k, x);                  // x = inv(M)[:,k]
    cd w[4];
    #pragma unroll
    for (int c=0;c<4;++c) w[c] = conj_(x[c]);
    double dre = 0.0;
    #pragma unroll
    for (int j=0;j<4;++j){
      cd tj = mkcd(0.0,0.0);
      #pragma unroll
      for (int c=0;c<4;++c) tj = cadd(tj, cmul(w[c], Vk[c][j]));
      dre += tj.re*w[j].re + tj.im*w[j].im;   // Re(tj * conj(w_j))
    }
    double inv_denom = rsqrt(dre > 0.0 ? dre : 1e-300);
    #pragma unroll
    for (int c=0;c<4;++c) W[k][c] = mkcd(w[c].re*inv_denom, w[c].im*inv_denom);
  }
  #pragma unroll
  for (int s=0;s<4;++s)
    #pragma unroll
    for (int c=0;c<4;++c) g_Wh[f*16+s*4+c] = make_float2((float)W[s][c].re, (float)W[s][c].im);

  if (do_scale){
    cd x[4];
    invcol4(W, 0, x);   // x = inv(Wh)[:,0]
    #pragma unroll
    for (int s=0;s<4;++s) g_scale[f*4+s] = make_float2((float)x[s].re, (float)x[s].im);
  }
}

// out[s,f,b] = (Wh[f] X[:,f,b])[s] * scale[f,s]; 2 b per thread, 8B packed stores
__global__ __launch_bounds__(256) void final_kernel(
    const float* __restrict__ Xr, const float* __restrict__ Xi,
    __hip_bfloat162* __restrict__ out){
  int t = blockIdx.x*blockDim.x + threadIdx.x;
  if (t >= B/2) return;
  int b = 2*t;
  int f0 = blockIdx.y*DFC, f1 = min(f0+DFC, F);
  for (int f=f0; f<f1; ++f){
    float2 xr[K], xi[K];
    #pragma unroll
    for (int c=0;c<K;++c){
      int idx = c*FB + f*B + b;
      xr[c] = *reinterpret_cast<const float2*>(Xr + idx);
      xi[c] = *reinterpret_cast<const float2*>(Xi + idx);
    }
    const float2* w = g_Wh + f*16;
    #pragma unroll
    for (int s=0;s<K;++s){
      float yr0=0.0f, yi0=0.0f, yr1=0.0f, yi1=0.0f;
      #pragma unroll
      for (int c=0;c<K;++c){
        float2 ww = w[s*4+c];
        yr0 += ww.x*xr[c].x - ww.y*xi[c].x;
        yi0 += ww.x*xi[c].x + ww.y*xr[c].x;
        yr1 += ww.x*xr[c].y - ww.y*xi[c].y;
        yi1 += ww.x*xi[c].y + ww.y*xr[c].y;
      }
      float2 sc = g_scale[f*4+s];
      union { __hip_bfloat162 h2[2]; uint2 u; } uu;
      uu.h2[0].x = __float2bfloat16(yr0*sc.x - yi0*sc.y);
      uu.h2[0].y = __float2bfloat16(yr0*sc.y + yi0*sc.x);
      uu.h2[1].x = __float2bfloat16(yr1*sc.x - yi1*sc.y);
      uu.h2[1].y = __float2bfloat16(yr1*sc.y + yi1*sc.x);
      *reinterpret_cast<uint2*>(out + s*FB + f*B + b) = uu.u;
    }
  }
}

// ---------------- launch ----------------------------------------------------
extern "C" void kernel_launch(void* const* d_in, const int* in_sizes, int n_in,
                              void* d_out, int out_size, void* d_ws, size_t ws_size,
                              hipStream_t stream){
  // Inputs arrive alphabetized: d_in[0]="Xi", d_in[1]="Xr".
  const float* Xr = (const float*)d_in[1];
  const float* Xi = (const float*)d_in[0];
  __hip_bfloat162* out = (__hip_bfloat162*)d_out;

  init_kernel<<<33, 256, 0, stream>>>();
  dim3 gD((B/2 + 255)/256, NDF);        // (8, 129)
  dim3 gP((B + 255)/256, K);            // (16, 4)
  dim3 gV(F, NBC);                      // (513, 8)
  int gR = (64*F + 255)/256;            // 129
  for (int it=0; it<NIT; ++it){
    demix_part_kernel<<<gD, 256, 0, stream>>>(Xr, Xi);
    phi_kernel<<<gP, 256, 0, stream>>>();
    v_kernel<<<gV, 256, 0, stream>>>(Xr, Xi);
    reduce_v_kernel<<<gR, 256, 0, stream>>>();
    update_kernel<<<(F + 63)/64, 64, 0, stream>>>(it == NIT-1 ? 1 : 0);
  }
  final_kernel<<<gD, 256, 0, stream>>>(Xr, Xi, out);
}